// Round 12
// baseline (580.139 us; speedup 1.0000x reference)
//
#include <hip/hip_runtime.h>
#include <hip/hip_bf16.h>

#define B_ 32
#define P_ 512
#define Q_ 64
#define E_ 300
#define KP 320          // E padded to multiple of 32 for MFMA K-steps
#define H_ 256
#define HH_ 128
#define NEG (-1e7f)
#define BP (B_*P_)
#define BQ (B_*Q_)

typedef __attribute__((ext_vector_type(8))) short bf16x8;
typedef __attribute__((ext_vector_type(4))) float f32x4;
typedef _Float16 half2v __attribute__((ext_vector_type(2)));
typedef unsigned int u32;

// ---- static device workspace (fully rewritten every call) ----
// Embeddings gathered T-MAJOR: row = t*32 + b
__device__ __hip_bfloat16 g_ep[BP][KP];
__device__ __hip_bfloat16 g_eq[BQ][KP];
__device__ __hip_bfloat16 g_wp[768][KP];     // combined passage wih
__device__ __hip_bfloat16 g_wq[768][KP];     // combined question wih
__device__ float g_biasp[768];               // bih (+ bhh for r,z gates)
__device__ float g_biasq[768];
__device__ float g_biasn[4][HH_];            // bhh n-gate bias per weight set
__device__ uint4 g_whhw[4*1024*6];           // [widx][tid=(j,o)][gate][2] f16-packed
__device__ float g_xtp[2L*P_*B_*384];        // passage x-proj, [dir][t][b][384] f32
__device__ float g_xtq[2L*Q_*B_*384];        // question x-proj
__device__ float g_penc[BP*H_];              // BiGRU passage encodings (f32)
__device__ float g_qenc[BQ*H_];              // BiGRU question encodings

struct PrepArgs { const float* wih[4]; const float* bih[4]; const float* bhh[4]; };

// ---------------- weight repack + bias fold ----------------
__global__ __launch_bounds__(64) void k_prepw(PrepArgs pa) {
    int r = blockIdx.x;                 // 0..1535
    int pq = r / 768, col = r % 768;
    int dir = col / 384, within = col % 384, gate = within / 128;
    int idx = pq * 2 + dir;             // {p_f,p_b,q_f,q_b}
    const float* wsrc = pa.wih[idx] + within * E_;
    __hip_bfloat16* dst = pq ? g_wq[col] : g_wp[col];
    for (int c = threadIdx.x; c < KP; c += 64)
        dst[c] = __float2bfloat16(c < E_ ? wsrc[c] : 0.f);
    if (threadIdx.x == 0) {
        float bsum = pa.bih[idx][within] + (gate < 2 ? pa.bhh[idx][within] : 0.f);
        (pq ? g_biasq : g_biasp)[col] = bsum;
        if (within >= 256) g_biasn[idx][within - 256] = pa.bhh[idx][within];
    }
}

// ---------------- whh -> per-thread f16-packed 16-wide k-slices ----------------
// thread tid=(j=tid>>3, o=tid&7) owns k-range [o*16, o*16+16) of rows
// {r,z,n gate} x col j: 6 uint4, contiguous per tid.
__global__ __launch_bounds__(1024) void k_prepw2(const float* w0, const float* w1,
                                                const float* w2, const float* w3) {
    int widx = blockIdx.x;              // 0..3
    const float* whh = widx == 0 ? w0 : widx == 1 ? w1 : widx == 2 ? w2 : w3;
    int tid = threadIdx.x;              // 0..1023
    int j = tid >> 3, o = tid & 7;
    uint4* dst = g_whhw + ((long)widx * 1024 + tid) * 6;
    for (int g = 0; g < 3; g++)
        for (int i = 0; i < 2; i++) {
            const float* src = whh + (long)(g * 128 + j) * HH_ + o * 16 + i * 8;
            u32 p[4];
            #pragma unroll
            for (int e = 0; e < 4; e++) {
                half2v hp;
                hp[0] = (_Float16)src[2 * e];
                hp[1] = (_Float16)src[2 * e + 1];
                p[e] = __builtin_bit_cast(u32, hp);
            }
            dst[g * 2 + i] = make_uint4(p[0], p[1], p[2], p[3]);
        }
}

// ---------------- embedding gather (T-MAJOR rows, f32 -> bf16) ----------------
__global__ __launch_bounds__(256) void k_gather(const int* pass, const int* ques, const float* emb) {
    int row = blockIdx.x * 4 + (threadIdx.x >> 6);
    int lane = threadIdx.x & 63;
    const int* tsrc; __hip_bfloat16* dst; int r, T;
    if (row < BP) { r = row; tsrc = pass; dst = &g_ep[r][0]; T = P_; }
    else          { r = row - BP; tsrc = ques; dst = &g_eq[r][0]; T = Q_; }
    int b = r & 31, t = r >> 5;         // t-major
    int tk = tsrc[b * T + t];
    const float* src = emb + (long)tk * E_;
    #pragma unroll
    for (int i = 0; i < 5; i++) {
        int c = i * 64 + lane;
        float v = (c < E_) ? src[c] : 0.f;
        dst[c] = __float2bfloat16(v);
    }
}

// ---------------- input-projection GEMM -> f32 [dir][t][b][384] (merged P+Q) ----------------
__global__ __launch_bounds__(256) void k_gemm() {
    int bx = blockIdx.x;
    int isQ = bx >= 128;
    int mblk = isQ ? bx - 128 : bx;
    const __hip_bfloat16* A  = isQ ? &g_eq[0][0] : &g_ep[0][0];
    const __hip_bfloat16* Bw = isQ ? &g_wq[0][0] : &g_wp[0][0];
    const float* bias = isQ ? g_biasq : g_biasp;
    float* Xt = isQ ? g_xtq : g_xtp;
    const int T = isQ ? Q_ : P_;
    __shared__ __hip_bfloat16 As[128][40];
    __shared__ __hip_bfloat16 Bs[128][40];
    int m0 = mblk * 128, n0 = blockIdx.y * 128;
    int tid = threadIdx.x, lane = tid & 63, w = tid >> 6;
    int wm = (w & 1) * 64, wn = (w >> 1) * 64;
    f32x4 acc[4][4] = {};
    int lr = tid >> 1, lc = (tid & 1) * 16;
    for (int kt = 0; kt < KP; kt += 32) {
        *(bf16x8*)&As[lr][lc]   = *(const bf16x8*)&A [(m0 + lr) * KP + kt + lc];
        *(bf16x8*)&As[lr][lc+8] = *(const bf16x8*)&A [(m0 + lr) * KP + kt + lc + 8];
        *(bf16x8*)&Bs[lr][lc]   = *(const bf16x8*)&Bw[(n0 + lr) * KP + kt + lc];
        *(bf16x8*)&Bs[lr][lc+8] = *(const bf16x8*)&Bw[(n0 + lr) * KP + kt + lc + 8];
        __syncthreads();
        int kb = (lane >> 4) * 8, l15 = lane & 15;
        bf16x8 af[4], bfr[4];
        #pragma unroll
        for (int i = 0; i < 4; i++) af[i]  = *(bf16x8*)&As[wm + i*16 + l15][kb];
        #pragma unroll
        for (int j = 0; j < 4; j++) bfr[j] = *(bf16x8*)&Bs[wn + j*16 + l15][kb];
        #pragma unroll
        for (int i = 0; i < 4; i++)
            #pragma unroll
            for (int j = 0; j < 4; j++)
                acc[i][j] = __builtin_amdgcn_mfma_f32_16x16x32_bf16(af[i], bfr[j], acc[i][j], 0, 0, 0);
        __syncthreads();
    }
    int l15 = lane & 15, lr4 = (lane >> 4) * 4;
    #pragma unroll
    for (int jj = 0; jj < 4; jj++) {
        int n = n0 + wn + jj * 16 + l15;
        float bn = bias[n];
        int dirn = n >= 384;
        int col = n - dirn * 384;
        float* Cx = Xt + (long)dirn * T * B_ * 384;
        #pragma unroll
        for (int i = 0; i < 4; i++) {
            int mb = m0 + wm + i * 16 + lr4;     // T-major rows: t = m>>5, b = m&31
            int t = mb >> 5, bb = mb & 31;
            #pragma unroll
            for (int q = 0; q < 4; q++)
                Cx[((long)t * B_ + bb + q) * 384 + col] = acc[i][jj][q] + bn;
        }
    }
}

// ---------------- z-gate poison for masked steps (freeze h exactly) ----------------
__global__ __launch_bounds__(128) void k_maskz(const int* pass, const int* ques) {
    int row = blockIdx.x;
    int tid = threadIdx.x;
    int isQ = row >= BP;
    int rr = isQ ? row - BP : row;
    int T = isQ ? Q_ : P_;
    int b = rr / T, t = rr % T;
    int tkn = isQ ? ques[rr] : pass[rr];
    if (tkn != 0) return;
    float* xt = isQ ? g_xtq : g_xtp;
    xt[((long)0 * T * B_ + (long)t * B_ + b) * 384 + 128 + tid] = 1e9f;
    xt[((long)1 * T * B_ + (long)t * B_ + b) * 384 + 128 + tid] = 1e9f;
}

// ---------------- GRU recurrence: 8-way K-split, 1024 threads/chain ----------------
// 128 blocks (one per chain) x 1024 threads (16 waves -> 4/SIMD). Thread (j,o)
// computes the o-th 16-wide k-slice of all 3 gate dots for col j (24 dot2,
// 6 resident uint4 weights), oct-reduces via shfl_xor 1/2/4 (DPP, intra-oct),
// computes gates redundantly; o==0 lane writes h (2B) + output (4B).
// h exchange: 2 ds_read_b128/thread (16 distinct addrs/wave = <=2-way aliasing,
// free), dbuf, one lgkm-only barrier per step.
#define D1(A, WU, HU) A = __builtin_amdgcn_fdot2( \
    __builtin_bit_cast(half2v, (WU)), __builtin_bit_cast(half2v, (HU)), A, false);
#define D4(A, W, H) D1(A,(W).x,(H).x) D1(A,(W).y,(H).y) D1(A,(W).z,(H).z) D1(A,(W).w,(H).w)

__global__ __launch_bounds__(1024, 1) void k_gru() {
    int blk = blockIdx.x;               // [isQ][dir][b]
    int isQ = blk >> 6, loc = blk & 63, dir = loc >> 5, b = loc & 31;
    const int T = isQ ? Q_ : P_;
    const float* xt = (isQ ? g_xtq : g_xtp) + (long)dir * T * B_ * 384;
    float* outp = isQ ? g_qenc : g_penc;
    int widx = isQ * 2 + dir;
    int tid = threadIdx.x;
    int j = tid >> 3, o = tid & 7;      // col 0..127, k-slice 0..7
    const uint4* wp = g_whhw + ((long)widx * 1024 + tid) * 6;
    uint4 wr0 = wp[0], wr1 = wp[1];
    uint4 wz0 = wp[2], wz1 = wp[3];
    uint4 wn0 = wp[4], wn1 = wp[5];
    float bnn = g_biasn[widx][j];
    __shared__ uint hbuf[2][64];        // h as packed f16 (256B), double-buffered
    int t0 = dir ? T - 1 : 0;
    int sdt = dir ? -(B_ * 384) : (B_ * 384);
    int sdo = dir ? -H_ : H_;
    int off = (t0 * B_ + b) * 384 + j;
    int ooff = (b * T + t0) * H_ + dir * HH_ + j;
    float xr = xt[off], xz = xt[off + 128], xn = xt[off + 256];
    uint4 z4 = {0u, 0u, 0u, 0u};
    uint4 h0 = z4, h1 = z4;
    float hold = 0.f;
    for (int st = 0; st < T; st++) {
        int offn = off + ((st + 1 < T) ? sdt : 0);
        float nxr = xt[offn], nxz = xt[offn + 128], nxn = xt[offn + 256];
        float ar0 = 0.f, ar1 = 0.f, az0 = 0.f, az1 = 0.f, an0 = 0.f, an1 = 0.f;
        D4(ar0, wr0, h0) D4(ar1, wr1, h1)
        D4(az0, wz0, h0) D4(az1, wz1, h1)
        D4(an0, wn0, h0) D4(an1, wn1, h1)
        // oct reduce over k-slices (lanes o^1, o^2, o^4 — same col j)
        float ar = ar0 + ar1, az = az0 + az1, an = an0 + an1;
        ar += __shfl_xor(ar, 1); ar += __shfl_xor(ar, 2); ar += __shfl_xor(ar, 4);
        az += __shfl_xor(az, 1); az += __shfl_xor(az, 2); az += __shfl_xor(az, 4);
        an += __shfl_xor(an, 1); an += __shfl_xor(an, 2); an += __shfl_xor(an, 4);
        // gates (masked steps: xz=1e9 -> z=1 -> h frozen exactly)
        float rg = __builtin_amdgcn_rcpf(1.f + __expf(-(ar + xr)));
        float zg = __builtin_amdgcn_rcpf(1.f + __expf(-(az + xz)));
        float ta = __builtin_amdgcn_fmed3f(fmaf(rg, an + bnn, xn), -15.f, 15.f);
        float e2 = __expf(2.f * ta);
        float th = fmaf(-2.f, __builtin_amdgcn_rcpf(e2 + 1.f), 1.f);
        float hv = fmaf(zg, hold - th, th);
        hold = hv;
        if (o == 0) {
            outp[ooff] = hv;                             // fire-and-forget store
            ((_Float16*)hbuf[st & 1])[j] = (_Float16)hv; // 2B h write
        }
        asm volatile("s_waitcnt lgkmcnt(0)\n\ts_barrier" ::: "memory");
        const uint4* hb = (const uint4*)hbuf[st & 1];
        h0 = hb[o * 2]; h1 = hb[o * 2 + 1];
        off = offn; ooff += sdo;
        xr = nxr; xz = nxz; xn = nxn;
    }
}

// ---------------- fused attention + output heads ----------------
#define QPAD 260
__global__ __launch_bounds__(256) void k_attn(const int* pass, const int* ques,
        const float* attn_w, const float* attn_b, const float* start_w,
        const float* start_b, const float* end_w, const float* end_b, float* out) {
    __shared__ float qs[Q_][QPAD];
    __shared__ float pw3[H_];
    __shared__ float lrow[Q_];
    __shared__ float probs[Q_];
    __shared__ float s2v[Q_];
    __shared__ int   qmS[Q_];
    __shared__ float red[4], redA[4], redB[4];
    __shared__ float awpart[4][QPAD];
    int b = blockIdx.x >> 6, pch = blockIdx.x & 63;
    int tid = threadIdx.x, lane = tid & 63, wid = tid >> 6;
    for (int i = tid; i < Q_ * H_; i += 256) {
        int q = i >> 8, h = i & 255;
        qs[q][h] = g_qenc[(long)(b * Q_ + q) * H_ + h];
    }
    if (tid < Q_) qmS[tid] = (ques[b * Q_ + tid] != 0);
    __syncthreads();
    int q4 = tid >> 2, part = tid & 3;
    {   // s2[q] = dot(qenc[q], w2)
        float p2 = 0.f;
        #pragma unroll 8
        for (int i = 0; i < 64; i++)
            p2 += qs[q4][part * 64 + i] * attn_w[256 + part * 64 + i];
        p2 += __shfl_xor(p2, 1);
        p2 += __shfl_xor(p2, 2);
        if (part == 0) s2v[q4] = p2;
    }
    __syncthreads();
    float ab = attn_b[0], sb = start_b[0], ebv = end_b[0];
    for (int pi = 0; pi < 8; pi++) {
        int p = pch * 8 + pi;
        float pv = g_penc[(long)(b * P_ + p) * H_ + tid];
        pw3[tid] = pv * attn_w[512 + tid];
        float r1 = pv * attn_w[tid];
        #pragma unroll
        for (int s = 1; s < 64; s <<= 1) r1 += __shfl_xor(r1, s);
        if (lane == 0) red[wid] = r1;
        __syncthreads();                                  // (A) pw3 + red
        float s1 = red[0] + red[1] + red[2] + red[3];
        float acc = 0.f;
        #pragma unroll
        for (int i = 0; i < 16; i++) {
            float4 qv = *(const float4*)&qs[q4][part * 64 + i * 4];
            float4 wv = *(const float4*)&pw3[part * 64 + i * 4];
            acc += qv.x * wv.x + qv.y * wv.y + qv.z * wv.z + qv.w * wv.w;
        }
        acc += __shfl_xor(acc, 1);
        acc += __shfl_xor(acc, 2);
        if (part == 0) lrow[q4] = qmS[q4] ? (s1 + s2v[q4] + acc + ab) : NEG;
        __syncthreads();                                  // (B) lrow
        if (tid < 64) {
            float v = lrow[tid];
            float m = v;
            #pragma unroll
            for (int s = 1; s < 64; s <<= 1) m = fmaxf(m, __shfl_xor(m, s));
            float e = __expf(v - m);
            float ss = e;
            #pragma unroll
            for (int s = 1; s < 64; s <<= 1) ss += __shfl_xor(ss, s);
            probs[tid] = e / ss;
        }
        __syncthreads();                                  // (C) probs
        float4 aw4 = {0.f, 0.f, 0.f, 0.f};
        #pragma unroll
        for (int qq = 0; qq < 16; qq++) {
            int q = wid * 16 + qq;
            float pq = probs[q];
            float4 qv = *(const float4*)&qs[q][lane * 4];
            aw4.x = fmaf(pq, qv.x, aw4.x);
            aw4.y = fmaf(pq, qv.y, aw4.y);
            aw4.z = fmaf(pq, qv.z, aw4.z);
            aw4.w = fmaf(pq, qv.w, aw4.w);
        }
        *(float4*)&awpart[wid][lane * 4] = aw4;
        __syncthreads();                                  // (D0) awpart
        float aw = awpart[0][tid] + awpart[1][tid] + awpart[2][tid] + awpart[3][tid];
        float spv = pv * start_w[tid] + aw * start_w[256 + tid] + pv * aw * start_w[512 + tid];
        float epv = pv * end_w[tid]   + aw * end_w[256 + tid]   + pv * aw * end_w[512 + tid];
        #pragma unroll
        for (int s = 1; s < 64; s <<= 1) {
            spv += __shfl_xor(spv, s);
            epv += __shfl_xor(epv, s);
        }
        if (lane == 0) { redA[wid] = spv; redB[wid] = epv; }
        __syncthreads();                                  // (D) redA/B
        if (tid == 0) {
            int pm = (pass[b * P_ + p] != 0);
            float sv = redA[0] + redA[1] + redA[2] + redA[3] + sb;
            float ev = redB[0] + redB[1] + redB[2] + redB[3] + ebv;
            out[b * P_ + p]       = pm ? sv : NEG;
            out[BP + b * P_ + p]  = pm ? ev : NEG;
        }
        __syncthreads();                                  // (E) end of row
    }
}

// ---------------- log_softmax over P per (batch, start/end) ----------------
__global__ __launch_bounds__(256) void k_lsm(float* out) {
    int b = blockIdx.x >> 1, which = blockIdx.x & 1;
    const float* src = out + which * BP + b * P_;
    int tid = threadIdx.x;
    float v0 = src[tid], v1 = src[tid + 256];
    __shared__ float red[4];
    float m = fmaxf(v0, v1);
    #pragma unroll
    for (int s = 1; s < 64; s <<= 1) m = fmaxf(m, __shfl_xor(m, s));
    if ((tid & 63) == 0) red[tid >> 6] = m;
    __syncthreads();
    m = fmaxf(fmaxf(red[0], red[1]), fmaxf(red[2], red[3]));
    __syncthreads();
    float ss = __expf(v0 - m) + __expf(v1 - m);
    #pragma unroll
    for (int s = 1; s < 64; s <<= 1) ss += __shfl_xor(ss, s);
    if ((tid & 63) == 0) red[tid >> 6] = ss;
    __syncthreads();
    float lse = m + logf(red[0] + red[1] + red[2] + red[3]);
    float* dst = out + (2 + which) * BP + b * P_;
    dst[tid] = v0 - lse;
    dst[tid + 256] = v1 - lse;
}

extern "C" void kernel_launch(void* const* d_in, const int* in_sizes, int n_in,
                              void* d_out, int out_size, void* d_ws, size_t ws_size,
                              hipStream_t stream) {
    const int* pass = (const int*)d_in[0];
    const int* ques = (const int*)d_in[1];
    const float* emb = (const float*)d_in[2];
    PrepArgs pa;
    const float* whh[4];
    const int base[4] = {3, 7, 11, 15};   // p_f, p_b, q_f, q_b blocks of 4 inputs
    for (int i = 0; i < 4; i++) {
        pa.wih[i] = (const float*)d_in[base[i] + 0];
        whh[i]    = (const float*)d_in[base[i] + 1];
        pa.bih[i] = (const float*)d_in[base[i] + 2];
        pa.bhh[i] = (const float*)d_in[base[i] + 3];
    }
    const float* attn_w  = (const float*)d_in[19];
    const float* attn_b  = (const float*)d_in[20];
    const float* start_w = (const float*)d_in[21];
    const float* start_b = (const float*)d_in[22];
    const float* end_w   = (const float*)d_in[23];
    const float* end_b   = (const float*)d_in[24];
    float* out = (float*)d_out;

    k_prepw <<<dim3(1536), dim3(64), 0, stream>>>(pa);
    k_prepw2<<<dim3(4), dim3(1024), 0, stream>>>(whh[0], whh[1], whh[2], whh[3]);
    k_gather<<<dim3((BP + BQ) / 4), dim3(256), 0, stream>>>(pass, ques, emb);
    k_gemm  <<<dim3(144, 6), dim3(256), 0, stream>>>();
    k_maskz <<<dim3(BP + BQ), dim3(128), 0, stream>>>(pass, ques);
    k_gru   <<<dim3(128), dim3(1024), 0, stream>>>();
    k_attn  <<<dim3(B_ * 64), dim3(256), 0, stream>>>(pass, ques, attn_w, attn_b,
                                                      start_w, start_b, end_w, end_b, out);
    k_lsm   <<<dim3(64), dim3(256), 0, stream>>>(out);
}

// Round 13
// 432.537 us; speedup vs baseline: 1.3412x; 1.3412x over previous
//
#include <hip/hip_runtime.h>
#include <hip/hip_bf16.h>

#define B_ 32
#define P_ 512
#define Q_ 64
#define E_ 300
#define KP 320          // E padded to multiple of 32 for MFMA K-steps
#define H_ 256
#define HH_ 128
#define NEG (-1e7f)
#define BP (B_*P_)
#define BQ (B_*Q_)

typedef __attribute__((ext_vector_type(8))) short bf16x8;
typedef __attribute__((ext_vector_type(4))) float f32x4;
typedef _Float16 half2v __attribute__((ext_vector_type(2)));
typedef unsigned int u32;

// ---- static device workspace (fully rewritten every call) ----
// Embeddings gathered T-MAJOR: row = t*32 + b
__device__ __hip_bfloat16 g_ep[BP][KP];
__device__ __hip_bfloat16 g_eq[BQ][KP];
__device__ __hip_bfloat16 g_wp[768][KP];     // combined passage wih
__device__ __hip_bfloat16 g_wq[768][KP];     // combined question wih
__device__ float g_biasp[768];               // bih (+ bhh for r,z gates)
__device__ float g_biasq[768];
__device__ float g_biasn[4][HH_];            // bhh n-gate bias per weight set
__device__ uint4 g_whhw[4*512*12];           // [widx][tid=(j,q)][gate][4] f16-packed
__device__ float g_xtp[2L*P_*B_*384];        // passage x-proj, [dir][t][b][384] f32
__device__ float g_xtq[2L*Q_*B_*384];        // question x-proj
__device__ float g_penc[BP*H_];              // BiGRU passage encodings (f32)
__device__ float g_qenc[BQ*H_];              // BiGRU question encodings

struct PrepArgs { const float* wih[4]; const float* bih[4]; const float* bhh[4]; };

// ---------------- weight repack + bias fold ----------------
__global__ __launch_bounds__(64) void k_prepw(PrepArgs pa) {
    int r = blockIdx.x;                 // 0..1535
    int pq = r / 768, col = r % 768;
    int dir = col / 384, within = col % 384, gate = within / 128;
    int idx = pq * 2 + dir;             // {p_f,p_b,q_f,q_b}
    const float* wsrc = pa.wih[idx] + within * E_;
    __hip_bfloat16* dst = pq ? g_wq[col] : g_wp[col];
    for (int c = threadIdx.x; c < KP; c += 64)
        dst[c] = __float2bfloat16(c < E_ ? wsrc[c] : 0.f);
    if (threadIdx.x == 0) {
        float bsum = pa.bih[idx][within] + (gate < 2 ? pa.bhh[idx][within] : 0.f);
        (pq ? g_biasq : g_biasp)[col] = bsum;
        if (within >= 256) g_biasn[idx][within - 256] = pa.bhh[idx][within];
    }
}

// ---------------- whh -> per-thread f16-packed quarter-rows (r11 layout) ----------------
__global__ __launch_bounds__(512) void k_prepw2(const float* w0, const float* w1,
                                               const float* w2, const float* w3) {
    int widx = blockIdx.x;              // 0..3
    const float* whh = widx == 0 ? w0 : widx == 1 ? w1 : widx == 2 ? w2 : w3;
    int tid = threadIdx.x;              // 0..511
    int j = tid >> 2, q = tid & 3;
    uint4* dst = g_whhw + ((long)widx * 512 + tid) * 12;
    for (int g = 0; g < 3; g++)
        for (int i = 0; i < 4; i++) {
            const float* src = whh + (long)(g * 128 + j) * HH_ + q * 32 + i * 8;
            u32 p[4];
            #pragma unroll
            for (int e = 0; e < 4; e++) {
                half2v hp;
                hp[0] = (_Float16)src[2 * e];
                hp[1] = (_Float16)src[2 * e + 1];
                p[e] = __builtin_bit_cast(u32, hp);
            }
            dst[g * 4 + i] = make_uint4(p[0], p[1], p[2], p[3]);
        }
}

// ---------------- embedding gather (T-MAJOR rows, f32 -> bf16) ----------------
__global__ __launch_bounds__(256) void k_gather(const int* pass, const int* ques, const float* emb) {
    int row = blockIdx.x * 4 + (threadIdx.x >> 6);
    int lane = threadIdx.x & 63;
    const int* tsrc; __hip_bfloat16* dst; int r, T;
    if (row < BP) { r = row; tsrc = pass; dst = &g_ep[r][0]; T = P_; }
    else          { r = row - BP; tsrc = ques; dst = &g_eq[r][0]; T = Q_; }
    int b = r & 31, t = r >> 5;         // t-major
    int tk = tsrc[b * T + t];
    const float* src = emb + (long)tk * E_;
    #pragma unroll
    for (int i = 0; i < 5; i++) {
        int c = i * 64 + lane;
        float v = (c < E_) ? src[c] : 0.f;
        dst[c] = __float2bfloat16(v);
    }
}

// ---------------- input-projection GEMM -> f32 [dir][t][b][384] (merged P+Q) ----------------
__global__ __launch_bounds__(256) void k_gemm() {
    int bx = blockIdx.x;
    int isQ = bx >= 128;
    int mblk = isQ ? bx - 128 : bx;
    const __hip_bfloat16* A  = isQ ? &g_eq[0][0] : &g_ep[0][0];
    const __hip_bfloat16* Bw = isQ ? &g_wq[0][0] : &g_wp[0][0];
    const float* bias = isQ ? g_biasq : g_biasp;
    float* Xt = isQ ? g_xtq : g_xtp;
    const int T = isQ ? Q_ : P_;
    __shared__ __hip_bfloat16 As[128][40];
    __shared__ __hip_bfloat16 Bs[128][40];
    int m0 = mblk * 128, n0 = blockIdx.y * 128;
    int tid = threadIdx.x, lane = tid & 63, w = tid >> 6;
    int wm = (w & 1) * 64, wn = (w >> 1) * 64;
    f32x4 acc[4][4] = {};
    int lr = tid >> 1, lc = (tid & 1) * 16;
    for (int kt = 0; kt < KP; kt += 32) {
        *(bf16x8*)&As[lr][lc]   = *(const bf16x8*)&A [(m0 + lr) * KP + kt + lc];
        *(bf16x8*)&As[lr][lc+8] = *(const bf16x8*)&A [(m0 + lr) * KP + kt + lc + 8];
        *(bf16x8*)&Bs[lr][lc]   = *(const bf16x8*)&Bw[(n0 + lr) * KP + kt + lc];
        *(bf16x8*)&Bs[lr][lc+8] = *(const bf16x8*)&Bw[(n0 + lr) * KP + kt + lc + 8];
        __syncthreads();
        int kb = (lane >> 4) * 8, l15 = lane & 15;
        bf16x8 af[4], bfr[4];
        #pragma unroll
        for (int i = 0; i < 4; i++) af[i]  = *(bf16x8*)&As[wm + i*16 + l15][kb];
        #pragma unroll
        for (int j = 0; j < 4; j++) bfr[j] = *(bf16x8*)&Bs[wn + j*16 + l15][kb];
        #pragma unroll
        for (int i = 0; i < 4; i++)
            #pragma unroll
            for (int j = 0; j < 4; j++)
                acc[i][j] = __builtin_amdgcn_mfma_f32_16x16x32_bf16(af[i], bfr[j], acc[i][j], 0, 0, 0);
        __syncthreads();
    }
    int l15 = lane & 15, lr4 = (lane >> 4) * 4;
    #pragma unroll
    for (int jj = 0; jj < 4; jj++) {
        int n = n0 + wn + jj * 16 + l15;
        float bn = bias[n];
        int dirn = n >= 384;
        int col = n - dirn * 384;
        float* Cx = Xt + (long)dirn * T * B_ * 384;
        #pragma unroll
        for (int i = 0; i < 4; i++) {
            int mb = m0 + wm + i * 16 + lr4;     // T-major rows: t = m>>5, b = m&31
            int t = mb >> 5, bb = mb & 31;
            #pragma unroll
            for (int q = 0; q < 4; q++)
                Cx[((long)t * B_ + bb + q) * 384 + col] = acc[i][jj][q] + bn;
        }
    }
}

// ---------------- z-gate poison for masked steps (grid-stride) ----------------
__global__ __launch_bounds__(256) void k_maskz(const int* pass, const int* ques) {
    int tid = threadIdx.x;
    for (int row = blockIdx.x; row < BP + BQ; row += 256) {
        int isQ = row >= BP;
        int rr = isQ ? row - BP : row;
        int T = isQ ? Q_ : P_;
        int tkn = isQ ? ques[rr] : pass[rr];
        if (tkn == 0) {
            int b = rr / T, t = rr % T;
            float* xt = isQ ? g_xtq : g_xtp;
            int dir = tid >> 7, col = tid & 127;
            xt[((long)dir * T * B_ + (long)t * B_ + b) * 384 + 128 + col] = 1e9f;
        }
    }
}

// ---------------- GRU recurrence: 4-way K-split, 512 threads/chain (r11) ----------------
#define D1(A, WU, HU) A = __builtin_amdgcn_fdot2( \
    __builtin_bit_cast(half2v, (WU)), __builtin_bit_cast(half2v, (HU)), A, false);
#define D4(A, W, H) D1(A,(W).x,(H).x) D1(A,(W).y,(H).y) D1(A,(W).z,(H).z) D1(A,(W).w,(H).w)

__global__ __launch_bounds__(512, 1) void k_gru() {
    int blk = blockIdx.x;               // [isQ][dir][b]
    int isQ = blk >> 6, loc = blk & 63, dir = loc >> 5, b = loc & 31;
    const int T = isQ ? Q_ : P_;
    const float* xt = (isQ ? g_xtq : g_xtp) + (long)dir * T * B_ * 384;
    float* outp = isQ ? g_qenc : g_penc;
    int widx = isQ * 2 + dir;
    int tid = threadIdx.x;
    int j = tid >> 2, q = tid & 3;      // col 0..127, k-quarter 0..3
    const uint4* wp = g_whhw + ((long)widx * 512 + tid) * 12;
    uint4 w00 = wp[0], w01 = wp[1], w02 = wp[2],  w03 = wp[3];
    uint4 w10 = wp[4], w11 = wp[5], w12 = wp[6],  w13 = wp[7];
    uint4 w20 = wp[8], w21 = wp[9], w22 = wp[10], w23 = wp[11];
    float bnn = g_biasn[widx][j];
    __shared__ uint hbuf[2][64];        // h as packed f16 (256B), double-buffered
    int t0 = dir ? T - 1 : 0;
    int sdt = dir ? -(B_ * 384) : (B_ * 384);
    int sdo = dir ? -H_ : H_;
    int off = (t0 * B_ + b) * 384 + j;
    int ooff = (b * T + t0) * H_ + dir * HH_ + j;
    float xr = xt[off], xz = xt[off + 128], xn = xt[off + 256];
    uint4 z4 = {0u, 0u, 0u, 0u};
    uint4 h0 = z4, h1 = z4, h2 = z4, h3 = z4;
    float hold = 0.f;
    for (int st = 0; st < T; st++) {
        int offn = off + ((st + 1 < T) ? sdt : 0);
        float nxr = xt[offn], nxz = xt[offn + 128], nxn = xt[offn + 256];
        float ar0 = 0.f, ar1 = 0.f, az0 = 0.f, az1 = 0.f, an0 = 0.f, an1 = 0.f;
        D4(ar0, w00, h0) D4(ar1, w01, h1) D4(ar0, w02, h2) D4(ar1, w03, h3)
        D4(az0, w10, h0) D4(az1, w11, h1) D4(az0, w12, h2) D4(az1, w13, h3)
        D4(an0, w20, h0) D4(an1, w21, h1) D4(an0, w22, h2) D4(an1, w23, h3)
        float ar = ar0 + ar1, az = az0 + az1, an = an0 + an1;
        ar += __shfl_xor(ar, 1); ar += __shfl_xor(ar, 2);
        az += __shfl_xor(az, 1); az += __shfl_xor(az, 2);
        an += __shfl_xor(an, 1); an += __shfl_xor(an, 2);
        float rg = __builtin_amdgcn_rcpf(1.f + __expf(-(ar + xr)));
        float zg = __builtin_amdgcn_rcpf(1.f + __expf(-(az + xz)));
        float ta = __builtin_amdgcn_fmed3f(fmaf(rg, an + bnn, xn), -15.f, 15.f);
        float e2 = __expf(2.f * ta);
        float th = fmaf(-2.f, __builtin_amdgcn_rcpf(e2 + 1.f), 1.f);
        float hv = fmaf(zg, hold - th, th);
        hold = hv;
        if (q == 0) {
            outp[ooff] = hv;                             // fire-and-forget store
            ((_Float16*)hbuf[st & 1])[j] = (_Float16)hv; // 2B h write
        }
        asm volatile("s_waitcnt lgkmcnt(0)\n\ts_barrier" ::: "memory");
        const uint4* hb = (const uint4*)hbuf[st & 1] + q * 4;
        h0 = hb[0]; h1 = hb[1]; h2 = hb[2]; h3 = hb[3];
        off = offn; ooff += sdo;
        xr = nxr; xz = nxz; xn = nxn;
    }
}

// ---------------- fused attention + output heads: wave-per-row, barrier-free ----------------
// 512 blocks (16/batch) x 256 thr. lane = q (Q=64=wave). Per wave: 8 p-rows,
// all reductions intra-wave (shfl), pw3/probs exchange via same-wave LDS with
// lgkmcnt-only waits. qenc staged once per block as f16 [64][288] (2-way banks).
#define QH 288
__global__ __launch_bounds__(256) void k_attn(const int* pass, const int* ques,
        const float* attn_w, const float* attn_b, const float* start_w,
        const float* start_b, const float* end_w, const float* end_b, float* out) {
    __shared__ _Float16 qsh[64][QH];    // 36,864 B
    __shared__ uint pw3u[4][128];       // per-wave pw3 as f16 pairs
    __shared__ _Float16 w2h[256];
    int b = blockIdx.x >> 4, pblk = blockIdx.x & 15;
    int tid = threadIdx.x, lane = tid & 63, wid = tid >> 6;
    {   // stage qenc (f32 -> f16)
        int q = tid >> 2, hb = (tid & 3) * 64;
        const float* src = g_qenc + ((long)(b * Q_ + q)) * H_ + hb;
        #pragma unroll
        for (int i = 0; i < 16; i++) {
            float4 v = *(const float4*)(src + i * 4);
            half2v a, c;
            a[0] = (_Float16)v.x; a[1] = (_Float16)v.y;
            c[0] = (_Float16)v.z; c[1] = (_Float16)v.w;
            uint2 pk = { __builtin_bit_cast(u32, a), __builtin_bit_cast(u32, c) };
            *(uint2*)&qsh[q][hb + i * 4] = pk;
        }
        if (tid < 128) {
            half2v a;
            a[0] = (_Float16)attn_w[256 + 2 * tid];
            a[1] = (_Float16)attn_w[256 + 2 * tid + 1];
            *(uint*)&w2h[2 * tid] = __builtin_bit_cast(u32, a);
        }
    }
    __syncthreads();                    // only barrier in the kernel
    int qm = ques[b * Q_ + lane] != 0;
    float s2;
    {
        float a0 = 0.f, a1 = 0.f;
        const uint4* qrow = (const uint4*)&qsh[lane][0];
        const uint4* wrow = (const uint4*)w2h;
        #pragma unroll
        for (int i = 0; i < 32; i++) {
            uint4 qv = qrow[i]; uint4 wv = wrow[i];
            D1(a0, qv.x, wv.x) D1(a1, qv.y, wv.y) D1(a0, qv.z, wv.z) D1(a1, qv.w, wv.w)
        }
        s2 = a0 + a1;
    }
    float4 w1 = *(const float4*)(attn_w + 4 * lane);
    float4 w3 = *(const float4*)(attn_w + 512 + 4 * lane);
    float4 sA = *(const float4*)(start_w + 4 * lane);
    float4 sB = *(const float4*)(start_w + 256 + 4 * lane);
    float4 sC = *(const float4*)(start_w + 512 + 4 * lane);
    float4 eA = *(const float4*)(end_w + 4 * lane);
    float4 eB = *(const float4*)(end_w + 256 + 4 * lane);
    float4 eC = *(const float4*)(end_w + 512 + 4 * lane);
    float ab = attn_b[0], sb = start_b[0], ebv = end_b[0];
    uint* mypw = pw3u[wid];
    const uint4* pwrow = (const uint4*)mypw;
    for (int r = 0; r < 8; r++) {
        int p = pblk * 32 + wid * 8 + r;
        long prow = (long)(b * P_ + p);
        int ptok = pass[prow];          // prefetched, used at the end
        float4 pv = *(const float4*)(g_penc + prow * H_ + 4 * lane);
        float s1p = pv.x * w1.x + pv.y * w1.y + pv.z * w1.z + pv.w * w1.w;
        #pragma unroll
        for (int s = 1; s < 64; s <<= 1) s1p += __shfl_xor(s1p, s);
        half2v h01, h23;
        h01[0] = (_Float16)(pv.x * w3.x); h01[1] = (_Float16)(pv.y * w3.y);
        h23[0] = (_Float16)(pv.z * w3.z); h23[1] = (_Float16)(pv.w * w3.w);
        mypw[2 * lane]     = __builtin_bit_cast(u32, h01);
        mypw[2 * lane + 1] = __builtin_bit_cast(u32, h23);
        asm volatile("s_waitcnt lgkmcnt(0)" ::: "memory");  // same-wave LDS visibility
        float c0 = 0.f, c1 = 0.f;
        const uint4* qrow = (const uint4*)&qsh[lane][0];
        #pragma unroll
        for (int i = 0; i < 32; i++) {
            uint4 qv = qrow[i]; uint4 wv = pwrow[i];
            D1(c0, qv.x, wv.x) D1(c1, qv.y, wv.y) D1(c0, qv.z, wv.z) D1(c1, qv.w, wv.w)
        }
        float logit = qm ? (s1p + s2 + c0 + c1 + ab) : NEG;
        float m = logit;
        #pragma unroll
        for (int s = 1; s < 64; s <<= 1) m = fmaxf(m, __shfl_xor(m, s));
        float e = __expf(logit - m);
        float ss = e;
        #pragma unroll
        for (int s = 1; s < 64; s <<= 1) ss += __shfl_xor(ss, s);
        float prob = e / ss;
        // attw for own h = 4*lane..4*lane+3 (packed f16 accum)
        half2v aw01 = {(_Float16)0.f, (_Float16)0.f}, aw23 = aw01;
        #pragma unroll 8
        for (int q2 = 0; q2 < 64; q2++) {
            float pq = __shfl(prob, q2);
            half2v ph; ph[0] = (_Float16)pq; ph[1] = ph[0];
            uint2 qv = *(const uint2*)&qsh[q2][4 * lane];
            aw01 += __builtin_bit_cast(half2v, qv.x) * ph;
            aw23 += __builtin_bit_cast(half2v, qv.y) * ph;
        }
        float a0 = (float)aw01[0], a1 = (float)aw01[1];
        float a2 = (float)aw23[0], a3 = (float)aw23[1];
        float spv = pv.x * sA.x + a0 * sB.x + pv.x * a0 * sC.x
                  + pv.y * sA.y + a1 * sB.y + pv.y * a1 * sC.y
                  + pv.z * sA.z + a2 * sB.z + pv.z * a2 * sC.z
                  + pv.w * sA.w + a3 * sB.w + pv.w * a3 * sC.w;
        float epv = pv.x * eA.x + a0 * eB.x + pv.x * a0 * eC.x
                  + pv.y * eA.y + a1 * eB.y + pv.y * a1 * eC.y
                  + pv.z * eA.z + a2 * eB.z + pv.z * a2 * eC.z
                  + pv.w * eA.w + a3 * eB.w + pv.w * a3 * eC.w;
        #pragma unroll
        for (int s = 1; s < 64; s <<= 1) {
            spv += __shfl_xor(spv, s);
            epv += __shfl_xor(epv, s);
        }
        if (lane == 0) {
            int pm = (ptok != 0);
            out[prow]      = pm ? (spv + sb)  : NEG;
            out[BP + prow] = pm ? (epv + ebv) : NEG;
        }
    }
}

// ---------------- log_softmax over P per (batch, start/end) ----------------
__global__ __launch_bounds__(256) void k_lsm(float* out) {
    int b = blockIdx.x >> 1, which = blockIdx.x & 1;
    const float* src = out + which * BP + b * P_;
    int tid = threadIdx.x;
    float v0 = src[tid], v1 = src[tid + 256];
    __shared__ float red[4];
    float m = fmaxf(v0, v1);
    #pragma unroll
    for (int s = 1; s < 64; s <<= 1) m = fmaxf(m, __shfl_xor(m, s));
    if ((tid & 63) == 0) red[tid >> 6] = m;
    __syncthreads();
    m = fmaxf(fmaxf(red[0], red[1]), fmaxf(red[2], red[3]));
    __syncthreads();
    float ss = __expf(v0 - m) + __expf(v1 - m);
    #pragma unroll
    for (int s = 1; s < 64; s <<= 1) ss += __shfl_xor(ss, s);
    if ((tid & 63) == 0) red[tid >> 6] = ss;
    __syncthreads();
    float lse = m + logf(red[0] + red[1] + red[2] + red[3]);
    float* dst = out + (2 + which) * BP + b * P_;
    dst[tid] = v0 - lse;
    dst[tid + 256] = v1 - lse;
}

extern "C" void kernel_launch(void* const* d_in, const int* in_sizes, int n_in,
                              void* d_out, int out_size, void* d_ws, size_t ws_size,
                              hipStream_t stream) {
    const int* pass = (const int*)d_in[0];
    const int* ques = (const int*)d_in[1];
    const float* emb = (const float*)d_in[2];
    PrepArgs pa;
    const float* whh[4];
    const int base[4] = {3, 7, 11, 15};   // p_f, p_b, q_f, q_b blocks of 4 inputs
    for (int i = 0; i < 4; i++) {
        pa.wih[i] = (const float*)d_in[base[i] + 0];
        whh[i]    = (const float*)d_in[base[i] + 1];
        pa.bih[i] = (const float*)d_in[base[i] + 2];
        pa.bhh[i] = (const float*)d_in[base[i] + 3];
    }
    const float* attn_w  = (const float*)d_in[19];
    const float* attn_b  = (const float*)d_in[20];
    const float* start_w = (const float*)d_in[21];
    const float* start_b = (const float*)d_in[22];
    const float* end_w   = (const float*)d_in[23];
    const float* end_b   = (const float*)d_in[24];
    float* out = (float*)d_out;

    k_prepw <<<dim3(1536), dim3(64), 0, stream>>>(pa);
    k_prepw2<<<dim3(4), dim3(512), 0, stream>>>(whh[0], whh[1], whh[2], whh[3]);
    k_gather<<<dim3((BP + BQ) / 4), dim3(256), 0, stream>>>(pass, ques, emb);
    k_gemm  <<<dim3(144, 6), dim3(256), 0, stream>>>();
    k_maskz <<<dim3(256), dim3(256), 0, stream>>>(pass, ques);
    k_gru   <<<dim3(128), dim3(512), 0, stream>>>();
    k_attn  <<<dim3(B_ * 16), dim3(256), 0, stream>>>(pass, ques, attn_w, attn_b,
                                                      start_w, start_b, end_w, end_b, out);
    k_lsm   <<<dim3(64), dim3(256), 0, stream>>>(out);
}

// Round 14
// 393.808 us; speedup vs baseline: 1.4732x; 1.0983x over previous
//
#include <hip/hip_runtime.h>
#include <hip/hip_bf16.h>

#define B_ 32
#define P_ 512
#define Q_ 64
#define E_ 300
#define KP 320          // E padded to multiple of 32 for MFMA K-steps
#define H_ 256
#define HH_ 128
#define NEG (-1e7f)
#define BP (B_*P_)
#define BQ (B_*Q_)

typedef __attribute__((ext_vector_type(8))) short bf16x8;
typedef __attribute__((ext_vector_type(4))) float f32x4;
typedef _Float16 half2v __attribute__((ext_vector_type(2)));
typedef unsigned int u32;

// ---- static device workspace (fully rewritten every call) ----
__device__ __hip_bfloat16 g_wp[768][KP];     // combined passage wih (bf16, K-padded)
__device__ __hip_bfloat16 g_wq[768][KP];     // combined question wih
__device__ float g_biasp[768];               // bih (+ bhh for r,z gates)
__device__ float g_biasq[768];
__device__ float g_biasn[4][HH_];            // bhh n-gate bias per weight set
__device__ uint4 g_whhw[4*512*12];           // [widx][tid=(j,q)][gate][4] f16-packed
__device__ _Float16 g_xtp[2L*P_*B_*384];     // passage x-proj, [dir][t][b][384] f16
__device__ _Float16 g_xtq[2L*Q_*B_*384];     // question x-proj (masked z cols = +inf)
__device__ float g_penc[BP*H_];              // BiGRU passage encodings (f32)
__device__ float g_qenc[BQ*H_];              // BiGRU question encodings

struct PrepArgs { const float* wih[4]; const float* whh[4]; const float* bih[4]; const float* bhh[4]; };

// ---------------- combined weight repack: wih->bf16 + bias fold + whh->f16 frags ----------------
__global__ __launch_bounds__(512) void k_prep(PrepArgs pa) {
    int blk = blockIdx.x;
    int tid = threadIdx.x;
    if (blk < 192) {                    // wih repack: 8 rows per block
        int r = blk * 8 + (tid >> 6);   // 0..1535
        int lane = tid & 63;
        int pq = r / 768, col = r % 768;
        int dir = col / 384, within = col % 384, gate = within / 128;
        int idx = pq * 2 + dir;         // {p_f,p_b,q_f,q_b}
        const float* wsrc = pa.wih[idx] + within * E_;
        __hip_bfloat16* dst = pq ? g_wq[col] : g_wp[col];
        for (int c = lane; c < KP; c += 64)
            dst[c] = __float2bfloat16(c < E_ ? wsrc[c] : 0.f);
        if (lane == 0) {
            float bsum = pa.bih[idx][within] + (gate < 2 ? pa.bhh[idx][within] : 0.f);
            (pq ? g_biasq : g_biasp)[col] = bsum;
            if (within >= 256) g_biasn[idx][within - 256] = pa.bhh[idx][within];
        }
    } else {                            // whh -> per-thread f16-packed quarter-rows
        int widx = blk - 192;           // 0..3
        const float* whh = pa.whh[widx];
        int j = tid >> 2, q = tid & 3;
        uint4* dst = g_whhw + ((long)widx * 512 + tid) * 12;
        for (int g = 0; g < 3; g++)
            for (int i = 0; i < 4; i++) {
                const float* src = whh + (long)(g * 128 + j) * HH_ + q * 32 + i * 8;
                u32 p[4];
                #pragma unroll
                for (int e = 0; e < 4; e++) {
                    half2v hp;
                    hp[0] = (_Float16)src[2 * e];
                    hp[1] = (_Float16)src[2 * e + 1];
                    p[e] = __builtin_bit_cast(u32, hp);
                }
                dst[g * 4 + i] = make_uint4(p[0], p[1], p[2], p[3]);
            }
    }
}

// ---------------- GEMM with fused embedding gather + f16 x-write + z-poison ----------------
// A staged directly from emb via token table (emb[0] is the zero padding row);
// epilogue writes f16 and poisons masked rows' z cols with +inf (exp(-inf)=0 -> z=1).
__global__ __launch_bounds__(256) void k_gemm(const int* pass, const int* ques, const float* emb) {
    int bx = blockIdx.x;
    int isQ = bx >= 128;
    int mblk = isQ ? bx - 128 : bx;
    const __hip_bfloat16* Bw = isQ ? &g_wq[0][0] : &g_wp[0][0];
    const float* bias = isQ ? g_biasq : g_biasp;
    _Float16* Xt = isQ ? g_xtq : g_xtp;
    const int* tsrc = isQ ? ques : pass;
    const int T = isQ ? Q_ : P_;
    __shared__ __hip_bfloat16 As[128][40];
    __shared__ __hip_bfloat16 Bs[128][40];
    __shared__ int toks[128];
    int m0 = mblk * 128, n0 = blockIdx.y * 128;
    int tid = threadIdx.x, lane = tid & 63, w = tid >> 6;
    int wm = (w & 1) * 64, wn = (w >> 1) * 64;
    if (tid < 128) {                    // token table for this M-tile (t-major rows)
        int m = m0 + tid;
        int t = m >> 5, bb = m & 31;
        toks[tid] = tsrc[bb * T + t];
    }
    f32x4 acc[4][4] = {};
    int lr = tid >> 1, lc = (tid & 1) * 16;
    __syncthreads();                    // toks visible
    long arow = (long)toks[lr] * E_;
    for (int kt = 0; kt < KP; kt += 32) {
        const float* er = emb + arow + kt + lc;
        __hip_bfloat16 a16[16];
        #pragma unroll
        for (int i = 0; i < 16; i++) {
            int c = kt + lc + i;
            a16[i] = __float2bfloat16((c < E_) ? er[i] : 0.f);
        }
        *(bf16x8*)&As[lr][lc]   = *(bf16x8*)&a16[0];
        *(bf16x8*)&As[lr][lc+8] = *(bf16x8*)&a16[8];
        *(bf16x8*)&Bs[lr][lc]   = *(const bf16x8*)&Bw[(n0 + lr) * KP + kt + lc];
        *(bf16x8*)&Bs[lr][lc+8] = *(const bf16x8*)&Bw[(n0 + lr) * KP + kt + lc + 8];
        __syncthreads();
        int kb = (lane >> 4) * 8, l15 = lane & 15;
        bf16x8 af[4], bfr[4];
        #pragma unroll
        for (int i = 0; i < 4; i++) af[i]  = *(bf16x8*)&As[wm + i*16 + l15][kb];
        #pragma unroll
        for (int j = 0; j < 4; j++) bfr[j] = *(bf16x8*)&Bs[wn + j*16 + l15][kb];
        #pragma unroll
        for (int i = 0; i < 4; i++)
            #pragma unroll
            for (int j = 0; j < 4; j++)
                acc[i][j] = __builtin_amdgcn_mfma_f32_16x16x32_bf16(af[i], bfr[j], acc[i][j], 0, 0, 0);
        __syncthreads();
    }
    int l15 = lane & 15, lr4 = (lane >> 4) * 4;
    const _Float16 inf16 = __builtin_bit_cast(_Float16, (unsigned short)0x7C00);
    #pragma unroll
    for (int jj = 0; jj < 4; jj++) {
        int n = n0 + wn + jj * 16 + l15;
        float bn = bias[n];
        int dirn = n >= 384;
        int col = n - dirn * 384;
        int zcol = (col >= 128) & (col < 256);
        _Float16* Cx = Xt + (long)dirn * T * B_ * 384;
        #pragma unroll
        for (int i = 0; i < 4; i++) {
            int mb = m0 + wm + i * 16 + lr4;     // T-major rows: t = m>>5, b = m&31
            int t = mb >> 5, bb = mb & 31;
            int lrow = wm + i * 16 + lr4;
            #pragma unroll
            for (int q = 0; q < 4; q++) {
                _Float16 v = (_Float16)(acc[i][jj][q] + bn);
                if (zcol && toks[lrow + q] == 0) v = inf16;   // freeze h at masked steps
                Cx[((long)t * B_ + bb + q) * 384 + col] = v;
            }
        }
    }
}

// ---------------- GRU recurrence: 4-way K-split, 512 threads/chain (r11) ----------------
#define D1(A, WU, HU) A = __builtin_amdgcn_fdot2( \
    __builtin_bit_cast(half2v, (WU)), __builtin_bit_cast(half2v, (HU)), A, false);
#define D4(A, W, H) D1(A,(W).x,(H).x) D1(A,(W).y,(H).y) D1(A,(W).z,(H).z) D1(A,(W).w,(H).w)

__global__ __launch_bounds__(512, 1) void k_gru() {
    int blk = blockIdx.x;               // [isQ][dir][b]
    int isQ = blk >> 6, loc = blk & 63, dir = loc >> 5, b = loc & 31;
    const int T = isQ ? Q_ : P_;
    const _Float16* xt = (isQ ? g_xtq : g_xtp) + (long)dir * T * B_ * 384;
    float* outp = isQ ? g_qenc : g_penc;
    int widx = isQ * 2 + dir;
    int tid = threadIdx.x;
    int j = tid >> 2, q = tid & 3;      // col 0..127, k-quarter 0..3
    const uint4* wp = g_whhw + ((long)widx * 512 + tid) * 12;
    uint4 w00 = wp[0], w01 = wp[1], w02 = wp[2],  w03 = wp[3];
    uint4 w10 = wp[4], w11 = wp[5], w12 = wp[6],  w13 = wp[7];
    uint4 w20 = wp[8], w21 = wp[9], w22 = wp[10], w23 = wp[11];
    float bnn = g_biasn[widx][j];
    __shared__ uint hbuf[2][64];        // h as packed f16 (256B), double-buffered
    int t0 = dir ? T - 1 : 0;
    int sdt = dir ? -(B_ * 384) : (B_ * 384);
    int sdo = dir ? -H_ : H_;
    int off = (t0 * B_ + b) * 384 + j;
    int ooff = (b * T + t0) * H_ + dir * HH_ + j;
    float xr = (float)xt[off], xz = (float)xt[off + 128], xn = (float)xt[off + 256];
    uint4 z4 = {0u, 0u, 0u, 0u};
    uint4 h0 = z4, h1 = z4, h2 = z4, h3 = z4;
    float hold = 0.f;
    for (int st = 0; st < T; st++) {
        int offn = off + ((st + 1 < T) ? sdt : 0);
        float nxr = (float)xt[offn], nxz = (float)xt[offn + 128], nxn = (float)xt[offn + 256];
        float ar0 = 0.f, ar1 = 0.f, az0 = 0.f, az1 = 0.f, an0 = 0.f, an1 = 0.f;
        D4(ar0, w00, h0) D4(ar1, w01, h1) D4(ar0, w02, h2) D4(ar1, w03, h3)
        D4(az0, w10, h0) D4(az1, w11, h1) D4(az0, w12, h2) D4(az1, w13, h3)
        D4(an0, w20, h0) D4(an1, w21, h1) D4(an0, w22, h2) D4(an1, w23, h3)
        float ar = ar0 + ar1, az = az0 + az1, an = an0 + an1;
        ar += __shfl_xor(ar, 1); ar += __shfl_xor(ar, 2);
        az += __shfl_xor(az, 1); az += __shfl_xor(az, 2);
        an += __shfl_xor(an, 1); an += __shfl_xor(an, 2);
        // gates (masked steps: xz=+inf -> z=1 -> h frozen exactly)
        float rg = __builtin_amdgcn_rcpf(1.f + __expf(-(ar + xr)));
        float zg = __builtin_amdgcn_rcpf(1.f + __expf(-(az + xz)));
        float ta = __builtin_amdgcn_fmed3f(fmaf(rg, an + bnn, xn), -15.f, 15.f);
        float e2 = __expf(2.f * ta);
        float th = fmaf(-2.f, __builtin_amdgcn_rcpf(e2 + 1.f), 1.f);
        float hv = fmaf(zg, hold - th, th);
        hold = hv;
        if (q == 0) {
            outp[ooff] = hv;                             // fire-and-forget store
            ((_Float16*)hbuf[st & 1])[j] = (_Float16)hv; // 2B h write
        }
        asm volatile("s_waitcnt lgkmcnt(0)\n\ts_barrier" ::: "memory");
        const uint4* hb = (const uint4*)hbuf[st & 1] + q * 4;
        h0 = hb[0]; h1 = hb[1]; h2 = hb[2]; h3 = hb[3];
        off = offn; ooff += sdo;
        xr = nxr; xz = nxz; xn = nxn;
    }
}

// ---------------- fused attention + output heads: wave-per-row, barrier-free ----------------
#define QH 288
__global__ __launch_bounds__(256) void k_attn(const int* pass, const int* ques,
        const float* attn_w, const float* attn_b, const float* start_w,
        const float* start_b, const float* end_w, const float* end_b, float* out) {
    __shared__ _Float16 qsh[64][QH];    // 36,864 B
    __shared__ uint pw3u[4][128];       // per-wave pw3 as f16 pairs
    __shared__ _Float16 w2h[256];
    int b = blockIdx.x >> 4, pblk = blockIdx.x & 15;
    int tid = threadIdx.x, lane = tid & 63, wid = tid >> 6;
    {   // stage qenc (f32 -> f16)
        int q = tid >> 2, hb = (tid & 3) * 64;
        const float* src = g_qenc + ((long)(b * Q_ + q)) * H_ + hb;
        #pragma unroll
        for (int i = 0; i < 16; i++) {
            float4 v = *(const float4*)(src + i * 4);
            half2v a, c;
            a[0] = (_Float16)v.x; a[1] = (_Float16)v.y;
            c[0] = (_Float16)v.z; c[1] = (_Float16)v.w;
            uint2 pk = { __builtin_bit_cast(u32, a), __builtin_bit_cast(u32, c) };
            *(uint2*)&qsh[q][hb + i * 4] = pk;
        }
        if (tid < 128) {
            half2v a;
            a[0] = (_Float16)attn_w[256 + 2 * tid];
            a[1] = (_Float16)attn_w[256 + 2 * tid + 1];
            *(uint*)&w2h[2 * tid] = __builtin_bit_cast(u32, a);
        }
    }
    __syncthreads();                    // only barrier in the kernel
    int qm = ques[b * Q_ + lane] != 0;
    float s2;
    {
        float a0 = 0.f, a1 = 0.f;
        const uint4* qrow = (const uint4*)&qsh[lane][0];
        const uint4* wrow = (const uint4*)w2h;
        #pragma unroll
        for (int i = 0; i < 32; i++) {
            uint4 qv = qrow[i]; uint4 wv = wrow[i];
            D1(a0, qv.x, wv.x) D1(a1, qv.y, wv.y) D1(a0, qv.z, wv.z) D1(a1, qv.w, wv.w)
        }
        s2 = a0 + a1;
    }
    float4 w1 = *(const float4*)(attn_w + 4 * lane);
    float4 w3 = *(const float4*)(attn_w + 512 + 4 * lane);
    float4 sA = *(const float4*)(start_w + 4 * lane);
    float4 sB = *(const float4*)(start_w + 256 + 4 * lane);
    float4 sC = *(const float4*)(start_w + 512 + 4 * lane);
    float4 eA = *(const float4*)(end_w + 4 * lane);
    float4 eB = *(const float4*)(end_w + 256 + 4 * lane);
    float4 eC = *(const float4*)(end_w + 512 + 4 * lane);
    float ab = attn_b[0], sb = start_b[0], ebv = end_b[0];
    uint* mypw = pw3u[wid];
    const uint4* pwrow = (const uint4*)mypw;
    for (int r = 0; r < 8; r++) {
        int p = pblk * 32 + wid * 8 + r;
        long prow = (long)(b * P_ + p);
        int ptok = pass[prow];          // prefetched, used at the end
        float4 pv = *(const float4*)(g_penc + prow * H_ + 4 * lane);
        float s1p = pv.x * w1.x + pv.y * w1.y + pv.z * w1.z + pv.w * w1.w;
        #pragma unroll
        for (int s = 1; s < 64; s <<= 1) s1p += __shfl_xor(s1p, s);
        half2v h01, h23;
        h01[0] = (_Float16)(pv.x * w3.x); h01[1] = (_Float16)(pv.y * w3.y);
        h23[0] = (_Float16)(pv.z * w3.z); h23[1] = (_Float16)(pv.w * w3.w);
        mypw[2 * lane]     = __builtin_bit_cast(u32, h01);
        mypw[2 * lane + 1] = __builtin_bit_cast(u32, h23);
        asm volatile("s_waitcnt lgkmcnt(0)" ::: "memory");  // same-wave LDS visibility
        float c0 = 0.f, c1 = 0.f;
        const uint4* qrow = (const uint4*)&qsh[lane][0];
        #pragma unroll
        for (int i = 0; i < 32; i++) {
            uint4 qv = qrow[i]; uint4 wv = pwrow[i];
            D1(c0, qv.x, wv.x) D1(c1, qv.y, wv.y) D1(c0, qv.z, wv.z) D1(c1, qv.w, wv.w)
        }
        float logit = qm ? (s1p + s2 + c0 + c1 + ab) : NEG;
        float m = logit;
        #pragma unroll
        for (int s = 1; s < 64; s <<= 1) m = fmaxf(m, __shfl_xor(m, s));
        float e = __expf(logit - m);
        float ss = e;
        #pragma unroll
        for (int s = 1; s < 64; s <<= 1) ss += __shfl_xor(ss, s);
        float prob = e / ss;
        // attw for own h = 4*lane..4*lane+3 (packed f16 accum)
        half2v aw01 = {(_Float16)0.f, (_Float16)0.f}, aw23 = aw01;
        #pragma unroll 8
        for (int q2 = 0; q2 < 64; q2++) {
            float pq = __shfl(prob, q2);
            half2v ph; ph[0] = (_Float16)pq; ph[1] = ph[0];
            uint2 qv = *(const uint2*)&qsh[q2][4 * lane];
            aw01 += __builtin_bit_cast(half2v, qv.x) * ph;
            aw23 += __builtin_bit_cast(half2v, qv.y) * ph;
        }
        float a0 = (float)aw01[0], a1 = (float)aw01[1];
        float a2 = (float)aw23[0], a3 = (float)aw23[1];
        float spv = pv.x * sA.x + a0 * sB.x + pv.x * a0 * sC.x
                  + pv.y * sA.y + a1 * sB.y + pv.y * a1 * sC.y
                  + pv.z * sA.z + a2 * sB.z + pv.z * a2 * sC.z
                  + pv.w * sA.w + a3 * sB.w + pv.w * a3 * sC.w;
        float epv = pv.x * eA.x + a0 * eB.x + pv.x * a0 * eC.x
                  + pv.y * eA.y + a1 * eB.y + pv.y * a1 * eC.y
                  + pv.z * eA.z + a2 * eB.z + pv.z * a2 * eC.z
                  + pv.w * eA.w + a3 * eB.w + pv.w * a3 * eC.w;
        #pragma unroll
        for (int s = 1; s < 64; s <<= 1) {
            spv += __shfl_xor(spv, s);
            epv += __shfl_xor(epv, s);
        }
        if (lane == 0) {
            int pm = (ptok != 0);
            out[prow]      = pm ? (spv + sb)  : NEG;
            out[BP + prow] = pm ? (epv + ebv) : NEG;
        }
    }
}

// ---------------- log_softmax over P per (batch, start/end) ----------------
__global__ __launch_bounds__(256) void k_lsm(float* out) {
    int b = blockIdx.x >> 1, which = blockIdx.x & 1;
    const float* src = out + which * BP + b * P_;
    int tid = threadIdx.x;
    float v0 = src[tid], v1 = src[tid + 256];
    __shared__ float red[4];
    float m = fmaxf(v0, v1);
    #pragma unroll
    for (int s = 1; s < 64; s <<= 1) m = fmaxf(m, __shfl_xor(m, s));
    if ((tid & 63) == 0) red[tid >> 6] = m;
    __syncthreads();
    m = fmaxf(fmaxf(red[0], red[1]), fmaxf(red[2], red[3]));
    __syncthreads();
    float ss = __expf(v0 - m) + __expf(v1 - m);
    #pragma unroll
    for (int s = 1; s < 64; s <<= 1) ss += __shfl_xor(ss, s);
    if ((tid & 63) == 0) red[tid >> 6] = ss;
    __syncthreads();
    float lse = m + logf(red[0] + red[1] + red[2] + red[3]);
    float* dst = out + (2 + which) * BP + b * P_;
    dst[tid] = v0 - lse;
    dst[tid + 256] = v1 - lse;
}

extern "C" void kernel_launch(void* const* d_in, const int* in_sizes, int n_in,
                              void* d_out, int out_size, void* d_ws, size_t ws_size,
                              hipStream_t stream) {
    const int* pass = (const int*)d_in[0];
    const int* ques = (const int*)d_in[1];
    const float* emb = (const float*)d_in[2];
    PrepArgs pa;
    const int base[4] = {3, 7, 11, 15};   // p_f, p_b, q_f, q_b blocks of 4 inputs
    for (int i = 0; i < 4; i++) {
        pa.wih[i] = (const float*)d_in[base[i] + 0];
        pa.whh[i] = (const float*)d_in[base[i] + 1];
        pa.bih[i] = (const float*)d_in[base[i] + 2];
        pa.bhh[i] = (const float*)d_in[base[i] + 3];
    }
    const float* attn_w  = (const float*)d_in[19];
    const float* attn_b  = (const float*)d_in[20];
    const float* start_w = (const float*)d_in[21];
    const float* start_b = (const float*)d_in[22];
    const float* end_w   = (const float*)d_in[23];
    const float* end_b   = (const float*)d_in[24];
    float* out = (float*)d_out;

    k_prep <<<dim3(196), dim3(512), 0, stream>>>(pa);
    k_gemm <<<dim3(144, 6), dim3(256), 0, stream>>>(pass, ques, emb);
    k_gru  <<<dim3(128), dim3(512), 0, stream>>>();
    k_attn <<<dim3(B_ * 16), dim3(256), 0, stream>>>(pass, ques, attn_w, attn_b,
                                                     start_w, start_b, end_w, end_b, out);
    k_lsm  <<<dim3(64), dim3(256), 0, stream>>>(out);
}